// Round 8
// baseline (144.271 us; speedup 1.0000x reference)
//
#include <hip/hip_runtime.h>
#include <hip/hip_bf16.h>

#define BSg   32
#define NAg   128
#define NEg   16256
#define EMBg  64
#define H1g   256

typedef __attribute__((ext_vector_type(8))) short  short8;
typedef __attribute__((ext_vector_type(4))) float  f32x4;

__device__ __forceinline__ unsigned short f2bf16u(float x) {
    union { __hip_bfloat16 h; unsigned short u; } cv;
    cv.h = __float2bfloat16(x);
    return cv.u;
}
// hardware packed f32x2 -> bf16x2 (v_cvt_pk_bf16_f32)
__device__ __forceinline__ unsigned int pack2(float a, float b) {
    union { __hip_bfloat162 h; unsigned int u; } cv;
    cv.h = __float22bfloat162_rn(make_float2(a, b));
    return cv.u;
}

// ---- pack mlp1_w1 fp32 -> bf16 in MFMA-B-fragment layout [K/8][N][8] ----
__global__ void pack_weights(const float* __restrict__ w1, unsigned short* __restrict__ w1p)
{
    int i = blockIdx.x * 256 + threadIdx.x;
    if (i < 320 * 256) {
        int k = i >> 8, n = i & 255;
        w1p[(k >> 3) * (256 * 8) + n * 8 + (k & 7)] = f2bf16u(w1[i]);
    }
}

// ---- edge pipeline, dst-major half-tiles: block = (b, dst, half), 4 waves (256 thr).
// One 64-edge A-tile (K=320 bf16) in LDS fragment-major [ks][m][lane][8]
// (lane-linear 16B slots -> conflict-free ds_write_b128/ds_read_b128). 40960 B
// -> exactly 4 blocks/CU: 4 independent barrier domains per CU (was 2).
// GEMM1 -> relu+bias -> column-sum -> in-block W2 matvec -> one atomicAdd per
// output element (halves combine in L2; ~2 MB total atomic traffic).
__global__ __launch_bounds__(256, 4) void edge_kernel(
    const float* __restrict__ x0, const float* __restrict__ x_last,
    const float* __restrict__ edge_attr, const float* __restrict__ conv_w,
    const float* __restrict__ conv_b, const unsigned short* __restrict__ w1p,
    const float* __restrict__ b1, const float* __restrict__ w2f,
    const float* __restrict__ b2, float* __restrict__ agg)
{
    __shared__ unsigned short fragA[10 * 4 * 64 * 8];   // 40960 B exactly

    // bijective XCD-chunked swizzle (8192 % 8 == 0): each XCD runs a contiguous
    // chunk of 1024 blocks = 4 batches -> per-batch edge_attr slice (~2 MB) L2-warm.
    const int wgid = (blockIdx.x & 7) * 1024 + (blockIdx.x >> 3);
    const int half = wgid & 1;
    const int bd   = wgid >> 1;          // b*128 + d
    const int b    = bd >> 7, d = bd & 127;

    const int tid  = threadIdx.x;
    const int wq   = tid >> 6, lane = tid & 63;
    const int llo  = lane & 15, lhi = lane >> 4;      // k-chunk owner == lhi
    const int colbase = wq * 64;

    // ---------- prefetch ks=0 B fragments (L2 latency overlaps build+barrier) ----------
    short8 bf0[4];
    #pragma unroll
    for (int n = 0; n < 4; ++n)
        bf0[n] = *(const short8*)&w1p[(lhi * H1g + colbase + n * 16 + llo) * 8];

    // ---------- build A tile (4 threads per edge; lane-linear LDS writes) ----------
    {
        const int j  = wq * 16 + llo;            // edge-in-tile 0..63
        const int el = half * 64 + j;            // edge ordinal for this dst, 0..127
        int s = el + (el >= d ? 1 : 0);          // src node (skip d)
        if (s > 127) s = 127;                    // pad row (el==127): clamp, masked later
        int e = s * 127 + d - (s < d ? 1 : 0);   // global edge index (src-major layout)
        if (e > NEg - 1) e = NEg - 1;

        const float4* nfp = (const float4*)(x0        + (((size_t)b * NAg + s) << 5) + (lhi << 3));
        const float4* eap = (const float4*)(edge_attr + (((size_t)b * NEg + e) << 5) + (lhi << 3));
        float4 nf0 = nfp[0], nf1 = nfp[1];
        float4 ea0 = eap[0], ea1 = eap[1];

        #pragma unroll
        for (int o = 0; o < 8; ++o) {
            const float w0 = conv_w[2 * o], w1v = conv_w[2 * o + 1], cb = conv_b[o];
            float y0 = fmaxf(fmaf(w0, nf0.x, fmaf(w1v, ea0.x, cb)), 0.f);
            float y1 = fmaxf(fmaf(w0, nf0.y, fmaf(w1v, ea0.y, cb)), 0.f);
            float y2 = fmaxf(fmaf(w0, nf0.z, fmaf(w1v, ea0.z, cb)), 0.f);
            float y3 = fmaxf(fmaf(w0, nf0.w, fmaf(w1v, ea0.w, cb)), 0.f);
            float y4 = fmaxf(fmaf(w0, nf1.x, fmaf(w1v, ea1.x, cb)), 0.f);
            float y5 = fmaxf(fmaf(w0, nf1.y, fmaf(w1v, ea1.y, cb)), 0.f);
            float y6 = fmaxf(fmaf(w0, nf1.z, fmaf(w1v, ea1.z, cb)), 0.f);
            float y7 = fmaxf(fmaf(w0, nf1.w, fmaf(w1v, ea1.w, cb)), 0.f);
            uint4 pk;
            pk.x = pack2(y0, y1); pk.y = pack2(y2, y3);
            pk.z = pack2(y4, y5); pk.w = pack2(y6, y7);
            // k = o*32 + lhi*8 -> block (ks=o, m=wq), slot low6 = lhi*16+llo = lane
            *(uint4*)&fragA[(((o * 4 + wq) * 64) + lane) * 8] = pk;
        }
        {
            const float4* lsp = (const float4*)(x_last + (((size_t)b * NAg + s) << 6) + (lhi << 4));
            float4 l0 = lsp[0], l1 = lsp[1], l2 = lsp[2], l3 = lsp[3];
            uint4 pa, pb;
            pa.x = pack2(l0.x, l0.y); pa.y = pack2(l0.z, l0.w);
            pa.z = pack2(l1.x, l1.y); pa.w = pack2(l1.z, l1.w);
            pb.x = pack2(l2.x, l2.y); pb.y = pack2(l2.z, l2.w);
            pb.z = pack2(l3.x, l3.y); pb.w = pack2(l3.z, l3.w);
            // k = 256 + lhi*16 + c : ks = 8+(lhi>>1), kchunk = (lhi&1)*2 (+1 for 2nd 8)
            const int ks8  = 8 + (lhi >> 1);
            const int slot = (ks8 * 4 + wq) * 64 + ((lhi & 1) * 2) * 16 + llo;
            *(uint4*)&fragA[slot * 8]        = pa;
            *(uint4*)&fragA[(slot + 16) * 8] = pb;
        }
    }
    __syncthreads();

    // ---------- GEMM1: [64x320] @ [320x256]; wave wq owns cols wq*64..+63 ----------
    f32x4 acc[4][4];
    #pragma unroll
    for (int m = 0; m < 4; ++m)
        #pragma unroll
        for (int n = 0; n < 4; ++n)
            acc[m][n] = (f32x4){0.f, 0.f, 0.f, 0.f};

    #pragma unroll
    for (int ks = 0; ks < 10; ++ks) {
        short8 af[4], bf[4];
        #pragma unroll
        for (int m = 0; m < 4; ++m)
            af[m] = *(const short8*)&fragA[((ks * 4 + m) * 64 + lane) * 8];
        #pragma unroll
        for (int n = 0; n < 4; ++n) {
            if (ks == 0) bf[n] = bf0[n];
            else         bf[n] = *(const short8*)&w1p[((ks * 4 + lhi) * H1g + colbase + n * 16 + llo) * 8];
        }
        #pragma unroll
        for (int m = 0; m < 4; ++m)
            #pragma unroll
            for (int n = 0; n < 4; ++n)
                acc[m][n] = __builtin_amdgcn_mfma_f32_16x16x32_bf16(af[m], bf[n], acc[m][n], 0, 0, 0);
    }

    // ---------- relu(+bias) and column-sum over the 64 rows (mask pad row el==127) ----------
    float h1s[4];
    {
        float bias1[4];
        #pragma unroll
        for (int n = 0; n < 4; ++n) bias1[n] = b1[colbase + n * 16 + llo];
        #pragma unroll
        for (int n = 0; n < 4; ++n) {
            float p = 0.f;
            #pragma unroll
            for (int m = 0; m < 4; ++m)
                #pragma unroll
                for (int i = 0; i < 4; ++i) {
                    float v = fmaxf(acc[m][n][i] + bias1[n], 0.f);
                    if (!(m == 3 && i == 3 && half == 1 && lhi == 3)) p += v;
                }
            p += __shfl_xor(p, 16, 64);
            p += __shfl_xor(p, 32, 64);
            h1s[n] = p;
        }
    }
    __syncthreads();   // all GEMM reads of fragA done -> safe to alias LDS

    float* h1part = (float*)fragA;          // [256] floats (bytes 0..1023)
    float* redS   = h1part + 256;           // [4][64]      (bytes 1024..2047)

    if (lhi == 0) {
        #pragma unroll
        for (int n = 0; n < 4; ++n) h1part[colbase + n * 16 + llo] = h1s[n];
    }
    __syncthreads();

    // ---------- matvec: partial agg[b,d,:] += h1part @ W2 (+ 127*b2 once) ----------
    {
        const int c = tid & 63, kq = tid >> 6;
        float p = 0.f;
        #pragma unroll 8
        for (int k0 = 0; k0 < 64; ++k0) {
            int k = kq * 64 + k0;
            p = fmaf(h1part[k], w2f[k * 64 + c], p);
        }
        redS[kq * 64 + c] = p;
    }
    __syncthreads();
    if (tid < 64) {
        float v = redS[tid] + redS[64 + tid] + redS[128 + tid] + redS[192 + tid];
        if (half == 0) v += 127.f * b2[tid];
        atomicAdd(&agg[((size_t)bd << 6) + tid], v);
    }
}

// ---- node pipeline (fp32, small): out = (relu([x0|x_last|agg] @ W1 + b1)) @ W2 + b2 ----
// 8 rows/block x 512 blocks -> 2 blocks/CU, latency hiding.
__global__ __launch_bounds__(256) void node_kernel(
    const float* __restrict__ x0, const float* __restrict__ x_last,
    const float* __restrict__ agg, const float* __restrict__ w1,
    const float* __restrict__ b1, const float* __restrict__ w2,
    const float* __restrict__ b2, float* __restrict__ out)
{
    __shared__ float lf[8][160];
    __shared__ float h2s[8][257];
    const int tid = threadIdx.x;
    const int r0  = blockIdx.x * 8;   // global node-row = b*128 + a

    for (int idx = tid; idx < 8 * 160; idx += 256) {
        int r = idx / 160, c = idx % 160;
        int gr = r0 + r;
        int bb = gr >> 7, a = gr & 127;
        float v;
        if (c < 32)      v = x0[(((size_t)bb * NAg + a) << 5) + c];
        else if (c < 96) v = x_last[(((size_t)bb * NAg + a) << 6) + (c - 32)];
        else             v = agg[((size_t)gr << 6) + (c - 96)];
        lf[r][c] = v;
    }
    __syncthreads();

    {   // layer 1: thread == output column
        const int c = tid;
        float acc[8];
        const float bb = b1[c];
        #pragma unroll
        for (int r = 0; r < 8; ++r) acc[r] = bb;
        for (int k = 0; k < 160; ++k) {
            float wv = w1[k * 256 + c];
            #pragma unroll
            for (int r = 0; r < 8; ++r) acc[r] = fmaf(lf[r][k], wv, acc[r]);
        }
        #pragma unroll
        for (int r = 0; r < 8; ++r) h2s[r][c] = fmaxf(acc[r], 0.f);
    }
    __syncthreads();

    {   // layer 2: thread -> (n = tid&63, 2 rows)
        const int n = tid & 63, rq = tid >> 6;
        float acc[2];
        const float bb = b2[n];
        #pragma unroll
        for (int j = 0; j < 2; ++j) acc[j] = bb;
        for (int k = 0; k < 256; ++k) {
            float wv = w2[k * 64 + n];
            #pragma unroll
            for (int j = 0; j < 2; ++j) acc[j] = fmaf(h2s[rq * 2 + j][k], wv, acc[j]);
        }
        #pragma unroll
        for (int j = 0; j < 2; ++j)
            out[((size_t)(r0 + rq * 2 + j) << 6) + n] = acc[j];
    }
}

extern "C" void kernel_launch(void* const* d_in, const int* in_sizes, int n_in,
                              void* d_out, int out_size, void* d_ws, size_t ws_size,
                              hipStream_t stream)
{
    const float* x0       = (const float*)d_in[0];
    const float* x_last   = (const float*)d_in[1];
    const float* edge_attr= (const float*)d_in[2];
    const float* conv_w   = (const float*)d_in[3];
    const float* conv_b   = (const float*)d_in[4];
    const float* mlp1_w1  = (const float*)d_in[5];
    const float* mlp1_b1  = (const float*)d_in[6];
    const float* mlp1_w2  = (const float*)d_in[7];
    const float* mlp1_b2  = (const float*)d_in[8];
    const float* mlp2_w1  = (const float*)d_in[9];
    const float* mlp2_b1  = (const float*)d_in[10];
    const float* mlp2_w2  = (const float*)d_in[11];
    const float* mlp2_b2  = (const float*)d_in[12];

    char* ws = (char*)d_ws;
    float* agg          = (float*)ws;                         // 1 MB, zero-init + atomics
    unsigned short* w1p = (unsigned short*)(ws + (1 << 20));  // 160 KB

    hipMemsetAsync(agg, 0, (size_t)BSg * NAg * EMBg * sizeof(float), stream);
    pack_weights<<<320, 256, 0, stream>>>(mlp1_w1, w1p);
    edge_kernel<<<BSg * NAg * 2, 256, 0, stream>>>(x0, x_last, edge_attr, conv_w, conv_b,
                                                   w1p, mlp1_b1, mlp1_w2, mlp1_b2, agg);
    node_kernel<<<(BSg * NAg) / 8, 256, 0, stream>>>(x0, x_last, agg, mlp2_w1, mlp2_b1,
                                                     mlp2_w2, mlp2_b2, (float*)d_out);
}

// Round 9
// 132.359 us; speedup vs baseline: 1.0900x; 1.0900x over previous
//
#include <hip/hip_runtime.h>
#include <hip/hip_bf16.h>

#define BSg   32
#define NAg   128
#define NEg   16256
#define EMBg  64
#define H1g   256

typedef __attribute__((ext_vector_type(8))) short  short8;
typedef __attribute__((ext_vector_type(4))) float  f32x4;

__device__ __forceinline__ unsigned short f2bf16u(float x) {
    union { __hip_bfloat16 h; unsigned short u; } cv;
    cv.h = __float2bfloat16(x);
    return cv.u;
}
// hardware packed f32x2 -> bf16x2 (v_cvt_pk_bf16_f32)
__device__ __forceinline__ unsigned int pack2(float a, float b) {
    union { __hip_bfloat162 h; unsigned int u; } cv;
    cv.h = __float22bfloat162_rn(make_float2(a, b));
    return cv.u;
}

// ---- pack mlp1_w1 fp32 -> bf16 in MFMA-B-fragment layout [K/8][N][8] ----
__global__ void pack_weights(const float* __restrict__ w1, unsigned short* __restrict__ w1p)
{
    int i = blockIdx.x * 256 + threadIdx.x;
    if (i < 320 * 256) {
        int k = i >> 8, n = i & 255;
        w1p[(k >> 3) * (256 * 8) + n * 8 + (k & 7)] = f2bf16u(w1[i]);
    }
}

// ---- edge pipeline, dst-major: block = (b, dst), 8 waves (512 thr).
// Waves 0-3: edges 0..63 of this dst; waves 4-7: edges 64..127 (concurrent halves).
// A tiles (64 edges x K=320 bf16 each) stored FRAGMENT-MAJOR: [ks][m][lane][8] shorts,
// lane-linear 16B slots -> conflict-free ds_write_b128 / ds_read_b128.
// GEMM1 B-operand is software-pipelined (depth-1 rotated register sets) so the
// ~200-cyc L2 latency of each ks's 4 global B-fragment loads hides under the
// previous ks's 16 MFMAs instead of serializing (R7 was stuck at VGPR=60 with
// no in-flight loads; this deliberately spends ~+50 VGPR on prefetch).
__global__ __launch_bounds__(512, 4) void edge_kernel(
    const float* __restrict__ x0, const float* __restrict__ x_last,
    const float* __restrict__ edge_attr, const float* __restrict__ conv_w,
    const float* __restrict__ conv_b, const unsigned short* __restrict__ w1p,
    const float* __restrict__ b1, const float* __restrict__ w2f,
    const float* __restrict__ b2, float* __restrict__ agg)
{
    __shared__ unsigned short fragA[2][10 * 4 * 64 * 8];   // 2 x 40960 B = 81920 B exactly

    const int tid  = threadIdx.x;
    const int b    = blockIdx.x >> 7;
    const int d    = blockIdx.x & 127;
    const int w8   = tid >> 6, lane = tid & 63;
    const int half = w8 >> 2, wq = w8 & 3;
    const int llo  = lane & 15, lhi = lane >> 4;      // k-chunk owner == lhi
    const int colbase = wq * 64;

    // ---------- prefetch ks=0 B fragments (L2 latency overlaps build+barrier) ----------
    short8 bfc[4], bfn[4];
    #pragma unroll
    for (int n = 0; n < 4; ++n)
        bfc[n] = *(const short8*)&w1p[(lhi * H1g + colbase + n * 16 + llo) * 8];

    // ---------- build A tile (4 threads per edge; lane-linear LDS writes) ----------
    {
        const int j  = wq * 16 + llo;            // edge-in-tile 0..63
        const int el = half * 64 + j;            // edge ordinal for this dst, 0..127
        int s = el + (el >= d ? 1 : 0);          // src node (skip d)
        if (s > 127) s = 127;                    // pad row: clamp, masked later
        int e = s * 127 + d - (s < d ? 1 : 0);   // global edge index (src-major layout)
        if (e > NEg - 1) e = NEg - 1;

        const float4* nfp = (const float4*)(x0        + (((size_t)b * NAg + s) << 5) + (lhi << 3));
        const float4* eap = (const float4*)(edge_attr + (((size_t)b * NEg + e) << 5) + (lhi << 3));
        float4 nf0 = nfp[0], nf1 = nfp[1];
        float4 ea0 = eap[0], ea1 = eap[1];

        #pragma unroll
        for (int o = 0; o < 8; ++o) {
            const float w0 = conv_w[2 * o], w1v = conv_w[2 * o + 1], cb = conv_b[o];
            float y0 = fmaxf(fmaf(w0, nf0.x, fmaf(w1v, ea0.x, cb)), 0.f);
            float y1 = fmaxf(fmaf(w0, nf0.y, fmaf(w1v, ea0.y, cb)), 0.f);
            float y2 = fmaxf(fmaf(w0, nf0.z, fmaf(w1v, ea0.z, cb)), 0.f);
            float y3 = fmaxf(fmaf(w0, nf0.w, fmaf(w1v, ea0.w, cb)), 0.f);
            float y4 = fmaxf(fmaf(w0, nf1.x, fmaf(w1v, ea1.x, cb)), 0.f);
            float y5 = fmaxf(fmaf(w0, nf1.y, fmaf(w1v, ea1.y, cb)), 0.f);
            float y6 = fmaxf(fmaf(w0, nf1.z, fmaf(w1v, ea1.z, cb)), 0.f);
            float y7 = fmaxf(fmaf(w0, nf1.w, fmaf(w1v, ea1.w, cb)), 0.f);
            uint4 pk;
            pk.x = pack2(y0, y1); pk.y = pack2(y2, y3);
            pk.z = pack2(y4, y5); pk.w = pack2(y6, y7);
            // k = o*32 + lhi*8 -> block (ks=o, m=wq), slot low6 = lhi*16+llo = lane
            *(uint4*)&fragA[half][(((o * 4 + wq) * 64) + lane) * 8] = pk;
        }
        {
            const float4* lsp = (const float4*)(x_last + (((size_t)b * NAg + s) << 6) + (lhi << 4));
            float4 l0 = lsp[0], l1 = lsp[1], l2 = lsp[2], l3 = lsp[3];
            uint4 pa, pb;
            pa.x = pack2(l0.x, l0.y); pa.y = pack2(l0.z, l0.w);
            pa.z = pack2(l1.x, l1.y); pa.w = pack2(l1.z, l1.w);
            pb.x = pack2(l2.x, l2.y); pb.y = pack2(l2.z, l2.w);
            pb.z = pack2(l3.x, l3.y); pb.w = pack2(l3.z, l3.w);
            // k = 256 + lhi*16 + c : ks = 8+(lhi>>1), kchunk = (lhi&1)*2 (+1 for 2nd 8)
            const int ks8  = 8 + (lhi >> 1);
            const int slot = (ks8 * 4 + wq) * 64 + ((lhi & 1) * 2) * 16 + llo;
            *(uint4*)&fragA[half][slot * 8]        = pa;
            *(uint4*)&fragA[half][(slot + 16) * 8] = pb;
        }
    }
    __syncthreads();

    // ---------- GEMM1: [64x320] @ [320x256]; wave (half,wq) owns cols wq*64..+63 ----------
    // Depth-1 software pipeline on B: loads for ks+1 issue before MFMAs of ks.
    f32x4 acc[4][4];
    #pragma unroll
    for (int m = 0; m < 4; ++m)
        #pragma unroll
        for (int n = 0; n < 4; ++n)
            acc[m][n] = (f32x4){0.f, 0.f, 0.f, 0.f};

    #pragma unroll
    for (int ks = 0; ks < 10; ++ks) {
        if (ks < 9) {
            #pragma unroll
            for (int n = 0; n < 4; ++n)
                bfn[n] = *(const short8*)&w1p[(((ks + 1) * 4 + lhi) * H1g + colbase + n * 16 + llo) * 8];
        }
        short8 af[4];
        #pragma unroll
        for (int m = 0; m < 4; ++m)
            af[m] = *(const short8*)&fragA[half][((ks * 4 + m) * 64 + lane) * 8];
        #pragma unroll
        for (int m = 0; m < 4; ++m)
            #pragma unroll
            for (int n = 0; n < 4; ++n)
                acc[m][n] = __builtin_amdgcn_mfma_f32_16x16x32_bf16(af[m], bfc[n], acc[m][n], 0, 0, 0);
        #pragma unroll
        for (int n = 0; n < 4; ++n) bfc[n] = bfn[n];
    }

    // ---------- relu(+bias) and column-sum over the 64 rows (mask pad row el==127) ----------
    float h1s[4];
    {
        float bias1[4];
        #pragma unroll
        for (int n = 0; n < 4; ++n) bias1[n] = b1[colbase + n * 16 + llo];
        #pragma unroll
        for (int n = 0; n < 4; ++n) {
            float p = 0.f;
            #pragma unroll
            for (int m = 0; m < 4; ++m)
                #pragma unroll
                for (int i = 0; i < 4; ++i) {
                    float v = fmaxf(acc[m][n][i] + bias1[n], 0.f);
                    if (!(m == 3 && i == 3) || !(half == 1 && lhi == 3)) p += v;
                }
            p += __shfl_xor(p, 16, 64);
            p += __shfl_xor(p, 32, 64);
            h1s[n] = p;
        }
    }
    __syncthreads();   // all GEMM reads of fragA done -> safe to alias LDS

    float* h1part = (float*)&fragA[0][0];   // [2][256]
    float* redS   = h1part + 512;           // [8][64]

    if (lhi == 0) {
        #pragma unroll
        for (int n = 0; n < 4; ++n) h1part[half * 256 + colbase + n * 16 + llo] = h1s[n];
    }
    __syncthreads();

    // ---------- matvec: agg[b,d,:] = (h0+h1) @ W2 + 127*b2 ----------
    {
        const int c = tid & 63, kq = tid >> 6;
        float p = 0.f;
        #pragma unroll 8
        for (int k0 = 0; k0 < 32; ++k0) {
            int k = kq * 32 + k0;
            float h = h1part[k] + h1part[256 + k];
            p = fmaf(h, w2f[k * 64 + c], p);
        }
        redS[kq * 64 + c] = p;
    }
    __syncthreads();
    if (tid < 64) {
        float v = redS[tid]       + redS[64 + tid]  + redS[128 + tid] + redS[192 + tid]
                + redS[256 + tid] + redS[320 + tid] + redS[384 + tid] + redS[448 + tid]
                + 127.f * b2[tid];
        agg[(((size_t)b * NAg + d) << 6) + tid] = v;
    }
}

// ---- node pipeline (fp32, small): out = (relu([x0|x_last|agg] @ W1 + b1)) @ W2 + b2 ----
// 8 rows/block x 512 blocks -> 2 blocks/CU, latency hiding.
__global__ __launch_bounds__(256) void node_kernel(
    const float* __restrict__ x0, const float* __restrict__ x_last,
    const float* __restrict__ agg, const float* __restrict__ w1,
    const float* __restrict__ b1, const float* __restrict__ w2,
    const float* __restrict__ b2, float* __restrict__ out)
{
    __shared__ float lf[8][160];
    __shared__ float h2s[8][257];
    const int tid = threadIdx.x;
    const int r0  = blockIdx.x * 8;   // global node-row = b*128 + a

    for (int idx = tid; idx < 8 * 160; idx += 256) {
        int r = idx / 160, c = idx % 160;
        int gr = r0 + r;
        int bb = gr >> 7, a = gr & 127;
        float v;
        if (c < 32)      v = x0[(((size_t)bb * NAg + a) << 5) + c];
        else if (c < 96) v = x_last[(((size_t)bb * NAg + a) << 6) + (c - 32)];
        else             v = agg[((size_t)gr << 6) + (c - 96)];
        lf[r][c] = v;
    }
    __syncthreads();

    {   // layer 1: thread == output column
        const int c = tid;
        float acc[8];
        const float bb = b1[c];
        #pragma unroll
        for (int r = 0; r < 8; ++r) acc[r] = bb;
        for (int k = 0; k < 160; ++k) {
            float wv = w1[k * 256 + c];
            #pragma unroll
            for (int r = 0; r < 8; ++r) acc[r] = fmaf(lf[r][k], wv, acc[r]);
        }
        #pragma unroll
        for (int r = 0; r < 8; ++r) h2s[r][c] = fmaxf(acc[r], 0.f);
    }
    __syncthreads();

    {   // layer 2: thread -> (n = tid&63, 2 rows)
        const int n = tid & 63, rq = tid >> 6;
        float acc[2];
        const float bb = b2[n];
        #pragma unroll
        for (int j = 0; j < 2; ++j) acc[j] = bb;
        for (int k = 0; k < 256; ++k) {
            float wv = w2[k * 64 + n];
            #pragma unroll
            for (int j = 0; j < 2; ++j) acc[j] = fmaf(h2s[rq * 2 + j][k], wv, acc[j]);
        }
        #pragma unroll
        for (int j = 0; j < 2; ++j)
            out[((size_t)(r0 + rq * 2 + j) << 6) + n] = acc[j];
    }
}

extern "C" void kernel_launch(void* const* d_in, const int* in_sizes, int n_in,
                              void* d_out, int out_size, void* d_ws, size_t ws_size,
                              hipStream_t stream)
{
    const float* x0       = (const float*)d_in[0];
    const float* x_last   = (const float*)d_in[1];
    const float* edge_attr= (const float*)d_in[2];
    const float* conv_w   = (const float*)d_in[3];
    const float* conv_b   = (const float*)d_in[4];
    const float* mlp1_w1  = (const float*)d_in[5];
    const float* mlp1_b1  = (const float*)d_in[6];
    const float* mlp1_w2  = (const float*)d_in[7];
    const float* mlp1_b2  = (const float*)d_in[8];
    const float* mlp2_w1  = (const float*)d_in[9];
    const float* mlp2_b1  = (const float*)d_in[10];
    const float* mlp2_w2  = (const float*)d_in[11];
    const float* mlp2_b2  = (const float*)d_in[12];

    char* ws = (char*)d_ws;
    float* agg          = (float*)ws;                         // 1 MB, fully overwritten
    unsigned short* w1p = (unsigned short*)(ws + (1 << 20));  // 160 KB

    pack_weights<<<320, 256, 0, stream>>>(mlp1_w1, w1p);
    edge_kernel<<<BSg * NAg, 512, 0, stream>>>(x0, x_last, edge_attr, conv_w, conv_b,
                                               w1p, mlp1_b1, mlp1_w2, mlp1_b2, agg);
    node_kernel<<<(BSg * NAg) / 8, 256, 0, stream>>>(x0, x_last, agg, mlp2_w1, mlp2_b1,
                                                     mlp2_w2, mlp2_b2, (float*)d_out);
}